// Round 3
// baseline (115.674 us; speedup 1.0000x reference)
//
#include <hip/hip_runtime.h>

// Smoothness loss, 1x3x224x224 f32, scalar f32 out. Single fused kernel:
// LDS halo tile (zero-padded -> no per-neighbor bounds checks, imm-offset
// ds_read_b64), 8 waves/block (4 window-row groups x 2 pixel rows),
// last-block final reduction via atomic counter in d_ws.

#define WSR 10
#define KK  21
#define HH  224
#define WW  224
#define HWSZ (HH*WW)
#define SIG_COLOR 50.0f          // 1/(0.1^2 * 2)
#define SIG_SPACE (1.0f/98.0f)   // 1/(7^2 * 2)
#define LPW 0.8f
#define C1T 10.0f
#define C2T 5.0f
#define ALPHA_W 5.0f
#define EPSV 1e-6f
#define LOG2E 1.44269504088896f

#define TX 64                    // tile width in pixels
#define TY 2                     // tile height in pixels
#define HALO_W (TX + 2*WSR)      // 84
#define HALO_H (TY + 2*WSR)      // 22
#define HSZ (HALO_W * HALO_H)    // 1848
#define NBX 4                    // 4*64 = 256 >= 224 (lane-masked)
#define NBY (HH / TY)            // 112
#define NBLK (NBX * NBY)         // 448

__device__ __forceinline__ float fexp2(float x) { return __builtin_amdgcn_exp2f(x); }
__device__ __forceinline__ float flog2(float x) { return __builtin_amdgcn_logf(x); }

__global__ __launch_bounds__(512) void smooth_loss_fused(
    const float* __restrict__ orig, const float* __restrict__ smo,
    float* __restrict__ partials, unsigned* __restrict__ counter,
    float* __restrict__ out)
{
    __shared__ float2 tA[HSZ];   // (o0, o1)
    __shared__ float2 tB[HSZ];   // (o2, s0)
    __shared__ float2 tC[HSZ];   // (s1, s2)
    __shared__ float w1[KK];
    __shared__ float racc0[512], racc1[512], racc2[512], racc3[512];
    __shared__ float red[2];
    __shared__ float red2[8];
    __shared__ int lastflag;

    const int tid = threadIdx.x;
    const int bid = blockIdx.x;
    const int bx  = bid & (NBX - 1);
    const int by  = bid >> 2;

    if (tid < KK) {
        float d = (float)(tid - WSR);
        w1[tid] = fexp2(-SIG_SPACE * LOG2E * d * d);
    }

    // ---- stage zero-padded halo tile (float2-packed planes) ----
    const int gx0 = bx * TX - WSR;
    const int gy0 = by * TY - WSR;
    for (int i = tid; i < HSZ; i += 512) {
        int r = i / HALO_W;
        int c = i - r * HALO_W;
        int gy = gy0 + r, gx = gx0 + c;
        bool v = ((unsigned)gy < (unsigned)HH) & ((unsigned)gx < (unsigned)WW);
        int gi = gy * WW + gx;
        float o0=0.f,o1=0.f,o2=0.f,s0=0.f,s1=0.f,s2=0.f;
        if (v) {
            o0 = orig[gi]; o1 = orig[gi+HWSZ]; o2 = orig[gi+2*HWSZ];
            s0 = smo[gi];  s1 = smo[gi+HWSZ];  s2 = smo[gi+2*HWSZ];
        }
        tA[i] = make_float2(o0,o1);
        tB[i] = make_float2(o2,s0);
        tC[i] = make_float2(s1,s2);
    }
    __syncthreads();

    // ---- main window scan: wave wv handles pixel-row (wv&1), rows kg,kg+4,... ----
    const int lane = tid & 63;
    const int wv   = tid >> 6;       // 0..7
    const int prow = wv & 1;
    const int kg   = wv >> 1;        // 0..3

    const int cpos = (prow + WSR) * HALO_W + (lane + WSR);
    const float2 cA = tA[cpos], cB = tB[cpos], cC = tC[cpos];
    const float oc0=cA.x, oc1=cA.y, oc2=cB.x, sc0=cB.y, sc1=cC.x, sc2=cC.y;

    float er_o=0.f, er_s=0.f, sl=0.f, ss=0.f;

    for (int ky = kg; ky < KK; ky += 4) {
        const float wy = w1[ky];
        const int rb = (prow + ky) * HALO_W + lane;
        #pragma unroll
        for (int kx = 0; kx < KK; ++kx) {
            float2 A = tA[rb + kx];
            float2 B = tB[rb + kx];
            float2 C = tC[rb + kx];
            float e0 = A.x - oc0, e1 = A.y - oc1, e2 = B.x - oc2;
            float a0 = (A.x > 0.f) ? fabsf(e0) : 0.f;
            float a1 = (A.y > 0.f) ? fabsf(e1) : 0.f;
            float a2 = (B.x > 0.f) ? fabsf(e2) : 0.f;
            er_o += a0 + a1 + a2;
            float t0 = (B.y > 0.f) ? fabsf(B.y - sc0) : 0.f;
            float t1 = (C.x > 0.f) ? fabsf(C.x - sc1) : 0.f;
            float t2 = (C.y > 0.f) ? fabsf(C.y - sc2) : 0.f;
            er_s += t0 + t1 + t2;
            float cd = e0*e0 + e1*e1 + e2*e2;
            float wr = fexp2(cd * (-SIG_COLOR * LOG2E));   // exp(-sig*cd)
            float wsp = wy * w1[kx];
            sl = fmaf(wsp, t0*t0 + t1*t1 + t2*t2, sl);
            float p0 = fexp2(LPW * flog2(t0 + EPSV));      // (t+eps)^0.8
            float p1 = fexp2(LPW * flog2(t1 + EPSV));
            float p2 = fexp2(LPW * flog2(t2 + EPSV));
            ss = fmaf(wr, p0 + p1 + p2, ss);
        }
    }

    racc0[tid]=er_o; racc1[tid]=er_s; racc2[tid]=sl; racc3[tid]=ss;
    __syncthreads();

    // ---- per-pixel combine (4 row-group threads), select, block reduce ----
    if (tid < 128) {
        float eo=0.f, es=0.f, l=0.f, s=0.f;
        #pragma unroll
        for (int k = 0; k < 4; ++k) {
            int t2i = lane + 64 * (prow + 2*k);   // prow==wv here (wv<2)
            eo += racc0[t2i]; es += racc1[t2i];
            l  += racc2[t2i]; s  += racc3[t2i];
        }
        bool use_large = (eo < C1T) && ((es - eo) > C2T);
        float contrib = use_large ? (ALPHA_W * l) : s;
        int px = bx * TX + lane;
        if (px >= WW) contrib = 0.f;
        #pragma unroll
        for (int off = 32; off > 0; off >>= 1)
            contrib += __shfl_down(contrib, off, 64);
        if (lane == 0) red[wv] = contrib;
    }
    __syncthreads();

    if (tid == 0) {
        partials[bid] = red[0] + red[1];
        __threadfence();
        unsigned old = atomicAdd(counter, 1u);
        lastflag = (old == (unsigned)(NBLK - 1)) ? 1 : 0;
    }
    __syncthreads();

    // ---- last block: final reduction ----
    if (lastflag) {
        float v = 0.f;
        for (int i = tid; i < NBLK; i += 512)
            v += atomicAdd(&partials[i], 0.0f);   // device-scope read
        #pragma unroll
        for (int off = 32; off > 0; off >>= 1)
            v += __shfl_down(v, off, 64);
        if (lane == 0) red2[wv] = v;
        __syncthreads();
        if (tid == 0) {
            float t = 0.f;
            #pragma unroll
            for (int k = 0; k < 8; ++k) t += red2[k];
            out[0] = t * (1.0f / ((float)HWSZ * (float)(WSR * WSR)));
        }
    }
}

extern "C" void kernel_launch(void* const* d_in, const int* in_sizes, int n_in,
                              void* d_out, int out_size, void* d_ws, size_t ws_size,
                              hipStream_t stream) {
    const float* orig = (const float*)d_in[0];   // original_images
    const float* smo  = (const float*)d_in[1];   // smooth_images
    float* out = (float*)d_out;

    unsigned* counter = (unsigned*)d_ws;                       // 4B at offset 0
    float* partials   = (float*)((char*)d_ws + 256);           // 448 floats

    hipMemsetAsync(d_ws, 0, 4, stream);                        // zero the counter
    smooth_loss_fused<<<NBLK, 512, 0, stream>>>(orig, smo, partials, counter, out);
}

// Round 5
// 101.315 us; speedup vs baseline: 1.1417x; 1.1417x over previous
//
#include <hip/hip_runtime.h>

// Smoothness loss, 1x3x224x224 f32, scalar f32 out. Single kernel + memset.
// LDS halo tile (zero-padded), 8 waves/block (4 window-row groups x 2 pixel
// rows), compile-time spatial-weight literals, row-factored sl accumulation,
// per-block atomicAdd to out.

#define WSR 10
#define KK  21
#define HH  224
#define WW  224
#define HWSZ (HH*WW)
#define SIG_COLOR 50.0f          // 1/(0.1^2 * 2)
#define LPW 0.8f
#define C1T 10.0f
#define C2T 5.0f
#define ALPHA_W 5.0f
#define EPSV 1e-6f
#define LOG2E 1.44269504088896f
#define NSC (-SIG_COLOR * LOG2E)     // exp(-sc*cd) = exp2(NSC*cd)
#define SSP ((1.0f/98.0f) * LOG2E)   // exp(-ss*d^2) = exp2(-SSP*d^2)

#define TX 64
#define TY 2
#define HALO_W (TX + 2*WSR)      // 84
#define HALO_H (TY + 2*WSR)      // 22
#define HSZ (HALO_W * HALO_H)    // 1848
#define NBX 4
#define NBY (HH / TY)            // 112
#define NBLK (NBX * NBY)         // 448
#define SCALEF (1.0f / ((float)HWSZ * 100.0f))

__device__ __forceinline__ float fexp2(float x) { return __builtin_amdgcn_exp2f(x); }
__device__ __forceinline__ float flog2(float x) { return __builtin_amdgcn_logf(x); }

// exp(-(k-10)^2/98), compile-time -> literal operands in the unrolled loop
static constexpr float WXT[KK] = {
  0.3604486f, 0.4375650f, 0.5204496f, 0.6065307f, 0.6925675f,
  0.7748383f, 0.8493658f, 0.9122539f, 0.9600054f, 0.9898479f,
  1.0f,
  0.9898479f, 0.9600054f, 0.9122539f, 0.8493658f, 0.7748383f,
  0.6925675f, 0.6065307f, 0.5204496f, 0.4375650f, 0.3604486f };

__global__ __launch_bounds__(512) void smooth_loss_fused(
    const float* __restrict__ orig, const float* __restrict__ smo,
    float* __restrict__ out)
{
    __shared__ float2 tA[HSZ];   // (o0, o1)
    __shared__ float2 tB[HSZ];   // (o2, s0)
    __shared__ float2 tC[HSZ];   // (s1, s2)
    __shared__ float racc0[512], racc1[512], racc2[512], racc3[512];
    __shared__ float red[2];

    const int tid = threadIdx.x;
    const int bid = blockIdx.x;
    const int bx  = bid & (NBX - 1);
    const int by  = bid >> 2;

    // ---- stage zero-padded halo tile ----
    const int gx0 = bx * TX - WSR;
    const int gy0 = by * TY - WSR;
    for (int i = tid; i < HSZ; i += 512) {
        int r = i / HALO_W;
        int c = i - r * HALO_W;
        int gy = gy0 + r, gx = gx0 + c;
        bool v = ((unsigned)gy < (unsigned)HH) & ((unsigned)gx < (unsigned)WW);
        int gi = gy * WW + gx;
        float o0=0.f,o1=0.f,o2=0.f,s0=0.f,s1=0.f,s2=0.f;
        if (v) {
            o0 = orig[gi]; o1 = orig[gi+HWSZ]; o2 = orig[gi+2*HWSZ];
            s0 = smo[gi];  s1 = smo[gi+HWSZ];  s2 = smo[gi+2*HWSZ];
        }
        tA[i] = make_float2(o0,o1);
        tB[i] = make_float2(o2,s0);
        tC[i] = make_float2(s1,s2);
    }
    __syncthreads();

    // ---- main window scan ----
    const int lane = tid & 63;
    const int wv   = tid >> 6;       // 0..7
    const int prow = wv & 1;         // pixel row within tile
    const int kg   = wv >> 1;        // window-row group 0..3 (rows kg, kg+4, ...)

    const int cpos = (prow + WSR) * HALO_W + (lane + WSR);
    const float2 cA = tA[cpos], cB = tB[cpos], cC = tC[cpos];
    const float oc0=cA.x, oc1=cA.y, oc2=cB.x, sc0=cB.y, sc1=cC.x, sc2=cC.y;

    float er_o=0.f, er_s=0.f, sl=0.f, ss=0.f;

    const int nrows = (kg == 0) ? 6 : 5;
    int ky = kg;
    for (int i = 0; i < nrows; ++i, ky += 4) {
        const float dy = (float)(ky - WSR);
        const float wy = fexp2(-SSP * dy * dy);
        const float2* __restrict__ rA = &tA[(prow + ky) * HALO_W + lane];
        const float2* __restrict__ rB = &tB[(prow + ky) * HALO_W + lane];
        const float2* __restrict__ rC = &tC[(prow + ky) * HALO_W + lane];
        float srow = 0.f;
        #pragma unroll
        for (int kx = 0; kx < KK; ++kx) {
            float2 A = rA[kx];
            float2 B = rB[kx];
            float2 C = rC[kx];
            float e0 = A.x - oc0, e1 = A.y - oc1, e2 = B.x - oc2;
            float a0 = (A.x > 0.f) ? fabsf(e0) : 0.f;
            float a1 = (A.y > 0.f) ? fabsf(e1) : 0.f;
            float a2 = (B.x > 0.f) ? fabsf(e2) : 0.f;
            er_o += (a0 + a1) + a2;
            float t0 = (B.y > 0.f) ? fabsf(B.y - sc0) : 0.f;
            float t1 = (C.x > 0.f) ? fabsf(C.x - sc1) : 0.f;
            float t2 = (C.y > 0.f) ? fabsf(C.y - sc2) : 0.f;
            er_s += (t0 + t1) + t2;
            float cd = fmaf(e0, e0, fmaf(e1, e1, e2*e2));
            float wr = fexp2(NSC * cd);                 // exp(-sig_color*cd)
            float tt = fmaf(t0, t0, fmaf(t1, t1, t2*t2));
            srow = fmaf(WXT[kx], tt, srow);             // literal weight
            float p0 = fexp2(LPW * flog2(t0 + EPSV));   // (t+eps)^0.8
            float p1 = fexp2(LPW * flog2(t1 + EPSV));
            float p2 = fexp2(LPW * flog2(t2 + EPSV));
            ss = fmaf(wr, (p0 + p1) + p2, ss);
        }
        sl = fmaf(wy, srow, sl);
    }

    racc0[tid]=er_o; racc1[tid]=er_s; racc2[tid]=sl; racc3[tid]=ss;
    __syncthreads();

    // ---- per-pixel combine (sum 4 row-groups), select, block reduce ----
    if (tid < 128) {
        float eo=0.f, es=0.f, l=0.f, s=0.f;
        #pragma unroll
        for (int k = 0; k < 4; ++k) {
            int t2i = lane + 64 * (prow + 2*k);   // prow==wv here (wv<2)
            eo += racc0[t2i]; es += racc1[t2i];
            l  += racc2[t2i]; s  += racc3[t2i];
        }
        bool use_large = (eo < C1T) && ((es - eo) > C2T);
        float contrib = use_large ? (ALPHA_W * l) : s;
        int px = bx * TX + lane;
        if (px >= WW) contrib = 0.f;                 // dead lanes of bx==3
        #pragma unroll
        for (int off = 32; off > 0; off >>= 1)
            contrib += __shfl_down(contrib, off, 64);
        if (lane == 0) red[wv] = contrib;
    }
    __syncthreads();

    if (tid == 0)
        atomicAdd(out, (red[0] + red[1]) * SCALEF);
}

extern "C" void kernel_launch(void* const* d_in, const int* in_sizes, int n_in,
                              void* d_out, int out_size, void* d_ws, size_t ws_size,
                              hipStream_t stream) {
    const float* orig = (const float*)d_in[0];   // original_images
    const float* smo  = (const float*)d_in[1];   // smooth_images
    float* out = (float*)d_out;

    hipMemsetAsync(d_out, 0, sizeof(float), stream);  // out accumulated via atomics
    smooth_loss_fused<<<NBLK, 512, 0, stream>>>(orig, smo, out);
}